// Round 3
// baseline (87.796 us; speedup 1.0000x reference)
//
#include <hip/hip_runtime.h>

#define BB 4
#define NN 4096
#define GG 1024
#define CC 32
#define NSIG 4
#define PVALS 132          // 128 acc + 4 dens per (b,g)
#define NT 128             // points per LDS tile
#define KS_PER_TILE (NT / 32)

// sigma = {0.01, 0.05, 0.1, 0.2} -> k = -0.5/sigma^2 = {-5000, -200, -50, -12.5}
// w(0.1)=w(0.2)^4, w(0.05)=w(0.1)^4 (repeated squaring); exp2 only for 0.2, 0.01.
#define C3 (-18.033688011112042f)   // -12.5/ln2  (sigma=0.2)
#define C0 (-7213.4752044448170f)   // -5000/ln2  (sigma=0.01)

typedef __attribute__((ext_vector_type(8))) short bf16x8;
typedef __attribute__((ext_vector_type(4))) float f32x4;

union frag_u { unsigned u[4]; bf16x8 v; };

// Proven bf16x2 pack (round-half-up via +0x8000, then perm high halves).
// NOTE: v_cvt_pk_bf16_f32 inline-asm was tried (R1/R2) and produced garbage
// densities on this toolchain — do NOT re-introduce without an isolated A/B.
__device__ __forceinline__ unsigned pack_bf16(float lo, float hi) {
    unsigned a = __float_as_uint(lo) + 0x8000u;
    unsigned b = __float_as_uint(hi) + 0x8000u;
    return __builtin_amdgcn_perm(b, a, 0x07060302u);
}

#define AS1 __attribute__((address_space(1)))
#define AS3 __attribute__((address_space(3)))
__device__ __forceinline__ void ld_lds16(const void* g, void* l) {
    __builtin_amdgcn_global_load_lds((const AS1 unsigned*)g, (AS3 unsigned*)l, 16, 0, 0);
}
__device__ __forceinline__ void ld_lds4(const void* g, void* l) {
    __builtin_amdgcn_global_load_lds((const AS1 unsigned*)g, (AS3 unsigned*)l, 4, 0, 0);
}

// ---- prep: feat*mask -> bf16 in MFMA-B-frag order; mask -> linear bf16 ----
// frag layout: element (b, n, c) -> row R=(b*(NN/32)+n/32)*2 + c/16 (1024 B rows),
// lane = ((n%32)/8)*16 + c%16, word = (n%8)/2, half = n%2.
__global__ __launch_bounds__(256) void gsc_prep_kernel(
    const float* __restrict__ pf, const float* __restrict__ pm,
    unsigned* __restrict__ fragw, unsigned* __restrict__ maskw)
{
    const int gid  = blockIdx.x * 256 + threadIdx.x;
    const int c    = gid & 31;
    const int rest = gid >> 5;
    const int np   = rest & (NN / 2 - 1);
    const int b    = rest >> 11;
    const int nl   = np * 2;
    const size_t ng = (size_t)b * NN + nl;
    const float m0 = pm[ng], m1 = pm[ng + 1];
    const float f0 = pf[ng * CC + c] * m0;
    const float f1 = pf[(ng + 1) * CC + c] * m1;
    const int ks = nl >> 5, qq = (nl >> 3) & 3, j = nl & 7, h = c >> 4;
    fragw[(((size_t)b * (NN / 32) + ks) * 2 + h) * 256 +
          (((qq << 4) | (c & 15)) << 2) + (j >> 1)] = pack_bf16(f0, f1);
    if (c == 0) maskw[ng >> 1] = pack_bf16(m0, m1);
}

struct __align__(16) TileBuf {
    unsigned feat[8 * 256];   // 8 frag rows x 1024 B
    float    x[NT];           // 512 B
    unsigned mask[64];        // 128 bf16
};

// ---- main: block = 4 waves, each wave owns 16 g's; async double-buffered
// staging via global_load_lds; A (weights) generated in-registers.
__global__ __launch_bounds__(256) void gsc_mfma_kernel(
    const float* __restrict__ px, const unsigned* __restrict__ fragw,
    const unsigned* __restrict__ maskw, const float* __restrict__ gx,
    float* __restrict__ partial, float* __restrict__ out0,
    float* __restrict__ out1, int nchunk, int direct)
{
    __shared__ TileBuf tiles[2];

    const int tid = threadIdx.x;
    const int w   = tid >> 6;
    const int l   = tid & 63;
    const int q   = l >> 4;
    const int cl  = l & 15;

    int bid = blockIdx.x;
    const int nc = bid % nchunk; bid /= nchunk;
    const int gg = bid % (GG / 64);
    const int b  = bid / (GG / 64);
    const int gbase = gg * 64 + w * 16;

    const float gxv = gx[gbase + cl];

    f32x4 acc[NSIG][2];
    f32x4 dacc[NSIG];
#pragma unroll
    for (int s = 0; s < NSIG; ++s) {
        acc[s][0] = (f32x4){0.f, 0.f, 0.f, 0.f};
        acc[s][1] = (f32x4){0.f, 0.f, 0.f, 0.f};
        dacc[s]   = (f32x4){0.f, 0.f, 0.f, 0.f};
    }

    const int chunk   = NN / nchunk;
    const int n_begin = nc * chunk;
    const int T       = chunk / NT;

    auto stage = [&](int t, int bufi) {
        TileBuf* tb = &tiles[bufi];
        const int n0 = n_begin + t * NT;
        // feat rows for this tile start at R = b*256 + n0/16 (1024 B each)
        const char* src = (const char*)fragw +
                          ((size_t)b * 256 + (n0 >> 4) + 2 * w) * 1024 + (size_t)l * 16;
        ld_lds16(src,        &tb->feat[(2 * w) * 256]);
        ld_lds16(src + 1024, &tb->feat[(2 * w + 1) * 256]);
        if (w == 0) {
            const float* xs = px + (size_t)b * NN + n0;
            ld_lds4(xs + l,      &tb->x[0]);
            ld_lds4(xs + 64 + l, &tb->x[64]);
        } else if (w == 1) {
            ld_lds4(maskw + (((size_t)b * NN + n0) >> 1) + l, &tb->mask[0]);
        }
    };

    auto compute = [&](int bufi) {
        TileBuf* tb = &tiles[bufi];
#pragma unroll
        for (int ks = 0; ks < KS_PER_TILE; ++ks) {
            const float4 xa = *(const float4*)&tb->x[ks * 32 + q * 8];
            const float4 xb = *(const float4*)&tb->x[ks * 32 + q * 8 + 4];
            float tt[8];
            float d;
            d = xa.x - gxv; tt[0] = d * d;
            d = xa.y - gxv; tt[1] = d * d;
            d = xa.z - gxv; tt[2] = d * d;
            d = xa.w - gxv; tt[3] = d * d;
            d = xb.x - gxv; tt[4] = d * d;
            d = xb.y - gxv; tt[5] = d * d;
            d = xb.z - gxv; tt[6] = d * d;
            d = xb.w - gxv; tt[7] = d * d;

            frag_u a0, a1, a2, a3;
#pragma unroll
            for (int j = 0; j < 8; j += 2) {
                const float w3a = __builtin_amdgcn_exp2f(tt[j]     * C3);
                const float w3b = __builtin_amdgcn_exp2f(tt[j + 1] * C3);
                float s;
                s = w3a * w3a; const float w2a = s * s;   // ^4 -> sigma 0.1
                s = w3b * w3b; const float w2b = s * s;
                s = w2a * w2a; const float w1a = s * s;   // ^4 -> sigma 0.05
                s = w2b * w2b; const float w1b = s * s;
                const float w0a = __builtin_amdgcn_exp2f(tt[j]     * C0);
                const float w0b = __builtin_amdgcn_exp2f(tt[j + 1] * C0);
                a3.u[j >> 1] = pack_bf16(w3a, w3b);
                a2.u[j >> 1] = pack_bf16(w2a, w2b);
                a1.u[j >> 1] = pack_bf16(w1a, w1b);
                a0.u[j >> 1] = pack_bf16(w0a, w0b);
            }

            const bf16x8 amv = *(const bf16x8*)((const char*)tb->mask + ks * 64 + q * 16);
            const bf16x8 bf0 = *(const bf16x8*)&tb->feat[(ks * 2 + 0) * 256 + l * 4];
            const bf16x8 bf1 = *(const bf16x8*)&tb->feat[(ks * 2 + 1) * 256 + l * 4];

            acc[0][0] = __builtin_amdgcn_mfma_f32_16x16x32_bf16(a0.v, bf0, acc[0][0], 0, 0, 0);
            acc[0][1] = __builtin_amdgcn_mfma_f32_16x16x32_bf16(a0.v, bf1, acc[0][1], 0, 0, 0);
            dacc[0]   = __builtin_amdgcn_mfma_f32_16x16x32_bf16(a0.v, amv, dacc[0], 0, 0, 0);
            acc[1][0] = __builtin_amdgcn_mfma_f32_16x16x32_bf16(a1.v, bf0, acc[1][0], 0, 0, 0);
            acc[1][1] = __builtin_amdgcn_mfma_f32_16x16x32_bf16(a1.v, bf1, acc[1][1], 0, 0, 0);
            dacc[1]   = __builtin_amdgcn_mfma_f32_16x16x32_bf16(a1.v, amv, dacc[1], 0, 0, 0);
            acc[2][0] = __builtin_amdgcn_mfma_f32_16x16x32_bf16(a2.v, bf0, acc[2][0], 0, 0, 0);
            acc[2][1] = __builtin_amdgcn_mfma_f32_16x16x32_bf16(a2.v, bf1, acc[2][1], 0, 0, 0);
            dacc[2]   = __builtin_amdgcn_mfma_f32_16x16x32_bf16(a2.v, amv, dacc[2], 0, 0, 0);
            acc[3][0] = __builtin_amdgcn_mfma_f32_16x16x32_bf16(a3.v, bf0, acc[3][0], 0, 0, 0);
            acc[3][1] = __builtin_amdgcn_mfma_f32_16x16x32_bf16(a3.v, bf1, acc[3][1], 0, 0, 0);
            dacc[3]   = __builtin_amdgcn_mfma_f32_16x16x32_bf16(a3.v, amv, dacc[3], 0, 0, 0);
        }
    };

    stage(0, 0);
#pragma unroll 1
    for (int t = 0; t < T; ++t) {
        __syncthreads();                       // drains tile t's loads
        if (t + 1 < T) stage(t + 1, (t + 1) & 1);  // fly during compute(t)
        compute(t & 1);
    }

    // ---- epilogue. C/D layout: col(c) = lane&15 (+16h), row(g) = quad*4+reg
    if (!direct) {
        float* p = partial + ((size_t)nc * BB * GG + (size_t)b * GG + gbase) * PVALS;
#pragma unroll
        for (int s = 0; s < NSIG; ++s)
#pragma unroll
            for (int h = 0; h < 2; ++h)
#pragma unroll
                for (int r = 0; r < 4; ++r)
                    p[(q * 4 + r) * PVALS + s * 32 + h * 16 + cl] = acc[s][h][r];
        if (cl == 0) {
#pragma unroll
            for (int s = 0; s < NSIG; ++s)
#pragma unroll
                for (int r = 0; r < 4; ++r)
                    p[(q * 4 + r) * PVALS + 128 + s] = dacc[s][r];
        }
    } else {
        float* o0 = out0 + ((size_t)b * GG + gbase) * (NSIG * CC);
        float* o1 = out1 + ((size_t)b * GG + gbase) * NSIG;
#pragma unroll
        for (int s = 0; s < NSIG; ++s)
#pragma unroll
            for (int r = 0; r < 4; ++r) {
                const float dd = dacc[s][r];
                const float inv = 1.0f / fmaxf(dd, 1e-6f);
#pragma unroll
                for (int h = 0; h < 2; ++h)
                    o0[(q * 4 + r) * (NSIG * CC) + s * CC + h * 16 + cl] = acc[s][h][r] * inv;
                if (cl == 0) o1[(q * 4 + r) * NSIG + s] = dd;
            }
    }
}

// ---- reduce: sum partials over n-chunks, divide, write final outputs ----
__global__ __launch_bounds__(128) void gsc_reduce_kernel(
    const float* __restrict__ partial, float* __restrict__ out0,
    float* __restrict__ out1, int nchunk)
{
    const size_t bg = blockIdx.x;
    const int v = threadIdx.x;   // 0..127 -> (s = v>>5, c = v&31)
    const int s = v >> 5;
    float num = 0.0f, dn = 0.0f;
    for (int nc = 0; nc < nchunk; ++nc) {
        const float* p = partial + ((size_t)nc * BB * GG + bg) * PVALS;
        num += p[v];
        dn  += p[128 + s];
    }
    out0[bg * 128 + v] = num / fmaxf(dn, 1e-6f);
    if (v < NSIG) {
        float d = 0.0f;
        for (int nc = 0; nc < nchunk; ++nc)
            d += partial[((size_t)nc * BB * GG + bg) * PVALS + 128 + v];
        out1[bg * NSIG + v] = d;
    }
}

extern "C" void kernel_launch(void* const* d_in, const int* in_sizes, int n_in,
                              void* d_out, int out_size, void* d_ws, size_t ws_size,
                              hipStream_t stream) {
    const float* px = (const float*)d_in[0];  // [B,N]
    const float* pf = (const float*)d_in[1];  // [B,N,C]
    const float* pm = (const float*)d_in[2];  // [B,N]
    const float* gx = (const float*)d_in[3];  // [G]
    float* out0 = (float*)d_out;                          // [B,G,4*C]
    float* out1 = out0 + (size_t)BB * GG * NSIG * CC;     // [B,G,4]

    const size_t fragWords = (size_t)BB * 256 * 256;   // 1 MB
    const size_t maskWords = (size_t)BB * NN / 2;      // 32 KB
    unsigned* fragw = (unsigned*)d_ws;
    unsigned* maskw = fragw + fragWords;
    float* partial  = (float*)(maskw + maskWords);
    const size_t used  = (fragWords + maskWords) * 4;
    const size_t avail = ws_size > used ? ws_size - used : 0;
    const size_t per   = (size_t)BB * GG * PVALS * sizeof(float);

    int nchunk = 1, direct = 1;
    if (8 * per <= avail)      { nchunk = 8; direct = 0; }
    else if (4 * per <= avail) { nchunk = 4; direct = 0; }
    else if (2 * per <= avail) { nchunk = 2; direct = 0; }
    else if (per <= avail)     { nchunk = 1; direct = 0; }

    gsc_prep_kernel<<<dim3(BB * (NN / 2) * CC / 256), dim3(256), 0, stream>>>(
        pf, pm, fragw, maskw);
    gsc_mfma_kernel<<<dim3(BB * (GG / 64) * nchunk), dim3(256), 0, stream>>>(
        px, fragw, maskw, gx, partial, out0, out1, nchunk, direct);
    if (!direct)
        gsc_reduce_kernel<<<dim3(BB * GG), dim3(128), 0, stream>>>(
            partial, out0, out1, nchunk);
}

// Round 4
// 84.014 us; speedup vs baseline: 1.0450x; 1.0450x over previous
//
#include <hip/hip_runtime.h>

#define BB 4
#define NN 4096
#define GG 1024
#define CC 32
#define NSIG 4
#define PVALS 132          // 128 acc + 4 dens per (b,g)
#define NT 128             // points per LDS tile
#define KS_PER_TILE (NT / 32)

// sigma = {0.01, 0.05, 0.1, 0.2} -> k = -0.5/sigma^2 = {-5000, -200, -50, -12.5}
// w(0.1)=w(0.2)^4, w(0.05)=w(0.1)^4 (repeated squaring); exp2 only for 0.2, 0.01.
#define C3 (-18.033688011112042f)   // -12.5/ln2  (sigma=0.2)
#define C0 (-7213.4752044448170f)   // -5000/ln2  (sigma=0.01)

typedef __attribute__((ext_vector_type(8))) short bf16x8;
typedef __attribute__((ext_vector_type(4))) float f32x4;

union frag_u { unsigned u[4]; bf16x8 v; };

// Proven bf16x2 pack (round-half-up via +0x8000, then perm high halves).
// NOTE: v_cvt_pk_bf16_f32 inline-asm was tried (R1/R2) and produced garbage
// densities on this toolchain — do NOT re-introduce without an isolated A/B.
__device__ __forceinline__ unsigned pack_bf16(float lo, float hi) {
    unsigned a = __float_as_uint(lo) + 0x8000u;
    unsigned b = __float_as_uint(hi) + 0x8000u;
    return __builtin_amdgcn_perm(b, a, 0x07060302u);
}

// Truncating pack: 1 VALU op instead of 3. Used ONLY for the in-loop A
// (weight) fragments: num and denom MFMAs consume the SAME truncated
// weights, so the num/denom ratio error cancels; density bias ~0.2%.
__device__ __forceinline__ unsigned pack_bf16_trunc(float lo, float hi) {
    return __builtin_amdgcn_perm(__float_as_uint(hi), __float_as_uint(lo),
                                 0x07060302u);
}

#define AS1 __attribute__((address_space(1)))
#define AS3 __attribute__((address_space(3)))
__device__ __forceinline__ void ld_lds16(const void* g, void* l) {
    __builtin_amdgcn_global_load_lds((const AS1 unsigned*)g, (AS3 unsigned*)l, 16, 0, 0);
}
__device__ __forceinline__ void ld_lds4(const void* g, void* l) {
    __builtin_amdgcn_global_load_lds((const AS1 unsigned*)g, (AS3 unsigned*)l, 4, 0, 0);
}

// ---- prep: feat*mask -> bf16 in MFMA-B-frag order; mask -> linear bf16 ----
// frag layout: element (b, n, c) -> row R=(b*(NN/32)+n/32)*2 + c/16 (1024 B rows),
// lane = ((n%32)/8)*16 + c%16, word = (n%8)/2, half = n%2.
__global__ __launch_bounds__(256) void gsc_prep_kernel(
    const float* __restrict__ pf, const float* __restrict__ pm,
    unsigned* __restrict__ fragw, unsigned* __restrict__ maskw)
{
    const int gid  = blockIdx.x * 256 + threadIdx.x;
    const int c    = gid & 31;
    const int rest = gid >> 5;
    const int np   = rest & (NN / 2 - 1);
    const int b    = rest >> 11;
    const int nl   = np * 2;
    const size_t ng = (size_t)b * NN + nl;
    const float m0 = pm[ng], m1 = pm[ng + 1];
    const float f0 = pf[ng * CC + c] * m0;
    const float f1 = pf[(ng + 1) * CC + c] * m1;
    const int ks = nl >> 5, qq = (nl >> 3) & 3, j = nl & 7, h = c >> 4;
    fragw[(((size_t)b * (NN / 32) + ks) * 2 + h) * 256 +
          (((qq << 4) | (c & 15)) << 2) + (j >> 1)] = pack_bf16(f0, f1);
    if (c == 0) maskw[ng >> 1] = pack_bf16(m0, m1);
}

struct __align__(16) TileBuf {
    unsigned feat[8 * 256];   // 8 frag rows x 1024 B
    float    x[NT];           // 512 B
    unsigned mask[64];        // 128 bf16
};

// ---- main: block = 4 waves, each wave owns 16 g's; async double-buffered
// staging via global_load_lds; A (weights) generated in-registers.
__global__ __launch_bounds__(256) void gsc_mfma_kernel(
    const float* __restrict__ px, const unsigned* __restrict__ fragw,
    const unsigned* __restrict__ maskw, const float* __restrict__ gx,
    float* __restrict__ partial, float* __restrict__ out0,
    float* __restrict__ out1, int nchunk, int direct)
{
    __shared__ TileBuf tiles[2];

    const int tid = threadIdx.x;
    const int w   = tid >> 6;
    const int l   = tid & 63;
    const int q   = l >> 4;
    const int cl  = l & 15;

    int bid = blockIdx.x;
    const int nc = bid % nchunk; bid /= nchunk;
    const int gg = bid % (GG / 64);
    const int b  = bid / (GG / 64);
    const int gbase = gg * 64 + w * 16;

    const float gxv = gx[gbase + cl];

    f32x4 acc[NSIG][2];
    f32x4 dacc[NSIG];
#pragma unroll
    for (int s = 0; s < NSIG; ++s) {
        acc[s][0] = (f32x4){0.f, 0.f, 0.f, 0.f};
        acc[s][1] = (f32x4){0.f, 0.f, 0.f, 0.f};
        dacc[s]   = (f32x4){0.f, 0.f, 0.f, 0.f};
    }

    const int chunk   = NN / nchunk;
    const int n_begin = nc * chunk;
    const int T       = chunk / NT;

    auto stage = [&](int t, int bufi) {
        TileBuf* tb = &tiles[bufi];
        const int n0 = n_begin + t * NT;
        // feat rows for this tile start at R = b*256 + n0/16 (1024 B each)
        const char* src = (const char*)fragw +
                          ((size_t)b * 256 + (n0 >> 4) + 2 * w) * 1024 + (size_t)l * 16;
        ld_lds16(src,        &tb->feat[(2 * w) * 256]);
        ld_lds16(src + 1024, &tb->feat[(2 * w + 1) * 256]);
        if (w == 0) {
            const float* xs = px + (size_t)b * NN + n0;
            ld_lds4(xs + l,      &tb->x[0]);
            ld_lds4(xs + 64 + l, &tb->x[64]);
        } else if (w == 1) {
            ld_lds4(maskw + (((size_t)b * NN + n0) >> 1) + l, &tb->mask[0]);
        }
    };

    auto compute = [&](int bufi) {
        TileBuf* tb = &tiles[bufi];
#pragma unroll
        for (int ks = 0; ks < KS_PER_TILE; ++ks) {
            const float4 xa = *(const float4*)&tb->x[ks * 32 + q * 8];
            const float4 xb = *(const float4*)&tb->x[ks * 32 + q * 8 + 4];
            float tt[8];
            float d;
            d = xa.x - gxv; tt[0] = d * d;
            d = xa.y - gxv; tt[1] = d * d;
            d = xa.z - gxv; tt[2] = d * d;
            d = xa.w - gxv; tt[3] = d * d;
            d = xb.x - gxv; tt[4] = d * d;
            d = xb.y - gxv; tt[5] = d * d;
            d = xb.z - gxv; tt[6] = d * d;
            d = xb.w - gxv; tt[7] = d * d;

            frag_u a0, a1, a2, a3;
#pragma unroll
            for (int j = 0; j < 8; j += 2) {
                const float w3a = __builtin_amdgcn_exp2f(tt[j]     * C3);
                const float w3b = __builtin_amdgcn_exp2f(tt[j + 1] * C3);
                float s;
                s = w3a * w3a; const float w2a = s * s;   // ^4 -> sigma 0.1
                s = w3b * w3b; const float w2b = s * s;
                s = w2a * w2a; const float w1a = s * s;   // ^4 -> sigma 0.05
                s = w2b * w2b; const float w1b = s * s;
                const float w0a = __builtin_amdgcn_exp2f(tt[j]     * C0);
                const float w0b = __builtin_amdgcn_exp2f(tt[j + 1] * C0);
                a3.u[j >> 1] = pack_bf16_trunc(w3a, w3b);
                a2.u[j >> 1] = pack_bf16_trunc(w2a, w2b);
                a1.u[j >> 1] = pack_bf16_trunc(w1a, w1b);
                a0.u[j >> 1] = pack_bf16_trunc(w0a, w0b);
            }

            const bf16x8 amv = *(const bf16x8*)((const char*)tb->mask + ks * 64 + q * 16);
            const bf16x8 bf0 = *(const bf16x8*)&tb->feat[(ks * 2 + 0) * 256 + l * 4];
            const bf16x8 bf1 = *(const bf16x8*)&tb->feat[(ks * 2 + 1) * 256 + l * 4];

            acc[0][0] = __builtin_amdgcn_mfma_f32_16x16x32_bf16(a0.v, bf0, acc[0][0], 0, 0, 0);
            acc[0][1] = __builtin_amdgcn_mfma_f32_16x16x32_bf16(a0.v, bf1, acc[0][1], 0, 0, 0);
            dacc[0]   = __builtin_amdgcn_mfma_f32_16x16x32_bf16(a0.v, amv, dacc[0], 0, 0, 0);
            acc[1][0] = __builtin_amdgcn_mfma_f32_16x16x32_bf16(a1.v, bf0, acc[1][0], 0, 0, 0);
            acc[1][1] = __builtin_amdgcn_mfma_f32_16x16x32_bf16(a1.v, bf1, acc[1][1], 0, 0, 0);
            dacc[1]   = __builtin_amdgcn_mfma_f32_16x16x32_bf16(a1.v, amv, dacc[1], 0, 0, 0);
            acc[2][0] = __builtin_amdgcn_mfma_f32_16x16x32_bf16(a2.v, bf0, acc[2][0], 0, 0, 0);
            acc[2][1] = __builtin_amdgcn_mfma_f32_16x16x32_bf16(a2.v, bf1, acc[2][1], 0, 0, 0);
            dacc[2]   = __builtin_amdgcn_mfma_f32_16x16x32_bf16(a2.v, amv, dacc[2], 0, 0, 0);
            acc[3][0] = __builtin_amdgcn_mfma_f32_16x16x32_bf16(a3.v, bf0, acc[3][0], 0, 0, 0);
            acc[3][1] = __builtin_amdgcn_mfma_f32_16x16x32_bf16(a3.v, bf1, acc[3][1], 0, 0, 0);
            dacc[3]   = __builtin_amdgcn_mfma_f32_16x16x32_bf16(a3.v, amv, dacc[3], 0, 0, 0);
        }
    };

    stage(0, 0);
#pragma unroll 1
    for (int t = 0; t < T; ++t) {
        __syncthreads();                       // drains tile t's loads
        if (t + 1 < T) stage(t + 1, (t + 1) & 1);  // fly during compute(t)
        compute(t & 1);
    }

    // ---- epilogue. C/D layout: col(c) = lane&15 (+16h), row(g) = quad*4+reg
    if (!direct) {
        float* p = partial + ((size_t)nc * BB * GG + (size_t)b * GG + gbase) * PVALS;
#pragma unroll
        for (int s = 0; s < NSIG; ++s)
#pragma unroll
            for (int h = 0; h < 2; ++h)
#pragma unroll
                for (int r = 0; r < 4; ++r)
                    p[(q * 4 + r) * PVALS + s * 32 + h * 16 + cl] = acc[s][h][r];
        if (cl == 0) {
#pragma unroll
            for (int s = 0; s < NSIG; ++s)
#pragma unroll
                for (int r = 0; r < 4; ++r)
                    p[(q * 4 + r) * PVALS + 128 + s] = dacc[s][r];
        }
    } else {
        float* o0 = out0 + ((size_t)b * GG + gbase) * (NSIG * CC);
        float* o1 = out1 + ((size_t)b * GG + gbase) * NSIG;
#pragma unroll
        for (int s = 0; s < NSIG; ++s)
#pragma unroll
            for (int r = 0; r < 4; ++r) {
                const float dd = dacc[s][r];
                const float inv = 1.0f / fmaxf(dd, 1e-6f);
#pragma unroll
                for (int h = 0; h < 2; ++h)
                    o0[(q * 4 + r) * (NSIG * CC) + s * CC + h * 16 + cl] = acc[s][h][r] * inv;
                if (cl == 0) o1[(q * 4 + r) * NSIG + s] = dd;
            }
    }
}

// ---- reduce: sum partials over n-chunks, divide, write final outputs ----
// nchunk==8 path fully unrolled so all 16 loads are in flight (the runtime
// trip count otherwise serializes 8 dependent load-waits).
__global__ __launch_bounds__(128) void gsc_reduce_kernel(
    const float* __restrict__ partial, float* __restrict__ out0,
    float* __restrict__ out1, int nchunk)
{
    const size_t bg = blockIdx.x;
    const int v = threadIdx.x;   // 0..127 -> (s = v>>5, c = v&31)
    const int s = v >> 5;
    const float* p0 = partial + bg * PVALS;
    const size_t cstride = (size_t)BB * GG * PVALS;
    float num = 0.0f, dn = 0.0f;
    if (nchunk == 8) {
#pragma unroll
        for (int nc = 0; nc < 8; ++nc) {
            const float* p = p0 + nc * cstride;
            num += p[v];
            dn  += p[128 + s];
        }
    } else {
        for (int nc = 0; nc < nchunk; ++nc) {
            const float* p = p0 + nc * cstride;
            num += p[v];
            dn  += p[128 + s];
        }
    }
    out0[bg * 128 + v] = num / fmaxf(dn, 1e-6f);
    if (v < NSIG) {
        float d = 0.0f;
        if (nchunk == 8) {
#pragma unroll
            for (int nc = 0; nc < 8; ++nc)
                d += p0[nc * cstride + 128 + v];
        } else {
            for (int nc = 0; nc < nchunk; ++nc)
                d += p0[nc * cstride + 128 + v];
        }
        out1[bg * NSIG + v] = d;
    }
}

extern "C" void kernel_launch(void* const* d_in, const int* in_sizes, int n_in,
                              void* d_out, int out_size, void* d_ws, size_t ws_size,
                              hipStream_t stream) {
    const float* px = (const float*)d_in[0];  // [B,N]
    const float* pf = (const float*)d_in[1];  // [B,N,C]
    const float* pm = (const float*)d_in[2];  // [B,N]
    const float* gx = (const float*)d_in[3];  // [G]
    float* out0 = (float*)d_out;                          // [B,G,4*C]
    float* out1 = out0 + (size_t)BB * GG * NSIG * CC;     // [B,G,4]

    const size_t fragWords = (size_t)BB * 256 * 256;   // 1 MB
    const size_t maskWords = (size_t)BB * NN / 2;      // 32 KB
    unsigned* fragw = (unsigned*)d_ws;
    unsigned* maskw = fragw + fragWords;
    float* partial  = (float*)(maskw + maskWords);
    const size_t used  = (fragWords + maskWords) * 4;
    const size_t avail = ws_size > used ? ws_size - used : 0;
    const size_t per   = (size_t)BB * GG * PVALS * sizeof(float);

    int nchunk = 1, direct = 1;
    if (8 * per <= avail)      { nchunk = 8; direct = 0; }
    else if (4 * per <= avail) { nchunk = 4; direct = 0; }
    else if (2 * per <= avail) { nchunk = 2; direct = 0; }
    else if (per <= avail)     { nchunk = 1; direct = 0; }

    gsc_prep_kernel<<<dim3(BB * (NN / 2) * CC / 256), dim3(256), 0, stream>>>(
        pf, pm, fragw, maskw);
    gsc_mfma_kernel<<<dim3(BB * (GG / 64) * nchunk), dim3(256), 0, stream>>>(
        px, fragw, maskw, gx, partial, out0, out1, nchunk, direct);
    if (!direct)
        gsc_reduce_kernel<<<dim3(BB * GG), dim3(128), 0, stream>>>(
            partial, out0, out1, nchunk);
}

// Round 5
// 79.980 us; speedup vs baseline: 1.0977x; 1.0504x over previous
//
#include <hip/hip_runtime.h>

#define BB 4
#define NN 4096
#define GG 1024
#define CC 32
#define NSIG 4
#define PVALS 68           // 64 packed-bf16x2 acc words + 4 f32 dens per (b,g)
#define NT 128             // points per LDS tile
#define KS_PER_TILE (NT / 32)

// sigma = {0.01, 0.05, 0.1, 0.2} -> k = -0.5/sigma^2 = {-5000, -200, -50, -12.5}
// w(0.1)=w(0.2)^4, w(0.05)=w(0.1)^4 (repeated squaring); exp2 only for 0.2, 0.01.
#define C3 (-18.033688011112042f)   // -12.5/ln2  (sigma=0.2)
#define C0 (-7213.4752044448170f)   // -5000/ln2  (sigma=0.01)

typedef __attribute__((ext_vector_type(8))) short bf16x8;
typedef __attribute__((ext_vector_type(4))) float f32x4;
typedef __attribute__((ext_vector_type(2))) float f32x2;

union frag_u { unsigned u[4]; bf16x8 v; };

// Proven bf16x2 pack (round-half-up via +0x8000, then perm high halves).
// Low 16 bits = bf16(lo), high 16 = bf16(hi).
// NOTE: v_cvt_pk_bf16_f32 inline-asm was tried (R1/R2) and produced garbage
// densities on this toolchain — do NOT re-introduce without an isolated A/B.
__device__ __forceinline__ unsigned pack_bf16(float lo, float hi) {
    unsigned a = __float_as_uint(lo) + 0x8000u;
    unsigned b = __float_as_uint(hi) + 0x8000u;
    return __builtin_amdgcn_perm(b, a, 0x07060302u);
}

// Truncating pack: 1 VALU op instead of 3. Used ONLY for the in-loop A
// (weight) fragments: num and denom MFMAs consume the SAME truncated
// weights, so the num/denom ratio error cancels; density bias ~0.2%.
__device__ __forceinline__ unsigned pack_bf16_trunc(float lo, float hi) {
    return __builtin_amdgcn_perm(__float_as_uint(hi), __float_as_uint(lo),
                                 0x07060302u);
}

#define AS1 __attribute__((address_space(1)))
#define AS3 __attribute__((address_space(3)))
__device__ __forceinline__ void ld_lds16(const void* g, void* l) {
    __builtin_amdgcn_global_load_lds((const AS1 unsigned*)g, (AS3 unsigned*)l, 16, 0, 0);
}
__device__ __forceinline__ void ld_lds4(const void* g, void* l) {
    __builtin_amdgcn_global_load_lds((const AS1 unsigned*)g, (AS3 unsigned*)l, 4, 0, 0);
}

// ---- prep: feat*mask -> bf16 in MFMA-B-frag order; mask -> linear bf16 ----
// frag layout: element (b, n, c) -> row R=(b*(NN/32)+n/32)*2 + c/16 (1024 B rows),
// lane = ((n%32)/8)*16 + c%16, word = (n%8)/2, half = n%2.
__global__ __launch_bounds__(256) void gsc_prep_kernel(
    const float* __restrict__ pf, const float* __restrict__ pm,
    unsigned* __restrict__ fragw, unsigned* __restrict__ maskw)
{
    const int gid  = blockIdx.x * 256 + threadIdx.x;
    const int c    = gid & 31;
    const int rest = gid >> 5;
    const int np   = rest & (NN / 2 - 1);
    const int b    = rest >> 11;
    const int nl   = np * 2;
    const size_t ng = (size_t)b * NN + nl;
    const float m0 = pm[ng], m1 = pm[ng + 1];
    const float f0 = pf[ng * CC + c] * m0;
    const float f1 = pf[(ng + 1) * CC + c] * m1;
    const int ks = nl >> 5, qq = (nl >> 3) & 3, j = nl & 7, h = c >> 4;
    fragw[(((size_t)b * (NN / 32) + ks) * 2 + h) * 256 +
          (((qq << 4) | (c & 15)) << 2) + (j >> 1)] = pack_bf16(f0, f1);
    if (c == 0) maskw[ng >> 1] = pack_bf16(m0, m1);
}

struct __align__(16) TileBuf {
    unsigned feat[8 * 256];   // 8 frag rows x 1024 B
    float    x[NT];           // 512 B
    unsigned mask[64];        // 128 bf16
};

// ---- main: block = 4 waves, each wave owns 16 g's; async double-buffered
// staging via global_load_lds; A (weights) generated in-registers.
__global__ __launch_bounds__(256) void gsc_mfma_kernel(
    const float* __restrict__ px, const unsigned* __restrict__ fragw,
    const unsigned* __restrict__ maskw, const float* __restrict__ gx,
    float* __restrict__ partial, float* __restrict__ out0,
    float* __restrict__ out1, int nchunk, int direct)
{
    __shared__ TileBuf tiles[2];

    const int tid = threadIdx.x;
    const int w   = tid >> 6;
    const int l   = tid & 63;
    const int q   = l >> 4;
    const int cl  = l & 15;

    int bid = blockIdx.x;
    const int nc = bid % nchunk; bid /= nchunk;
    const int gg = bid % (GG / 64);
    const int b  = bid / (GG / 64);
    const int gbase = gg * 64 + w * 16;

    const float gxv = gx[gbase + cl];
    const f32x2 gx2 = {gxv, gxv};
    const f32x2 c3v = {C3, C3};
    const f32x2 c0v = {C0, C0};

    f32x4 acc[NSIG][2];
    f32x4 dacc[NSIG];
#pragma unroll
    for (int s = 0; s < NSIG; ++s) {
        acc[s][0] = (f32x4){0.f, 0.f, 0.f, 0.f};
        acc[s][1] = (f32x4){0.f, 0.f, 0.f, 0.f};
        dacc[s]   = (f32x4){0.f, 0.f, 0.f, 0.f};
    }

    const int chunk   = NN / nchunk;
    const int n_begin = nc * chunk;
    const int T       = chunk / NT;

    auto stage = [&](int t, int bufi) {
        TileBuf* tb = &tiles[bufi];
        const int n0 = n_begin + t * NT;
        // feat rows for this tile start at R = b*256 + n0/16 (1024 B each)
        const char* src = (const char*)fragw +
                          ((size_t)b * 256 + (n0 >> 4) + 2 * w) * 1024 + (size_t)l * 16;
        ld_lds16(src,        &tb->feat[(2 * w) * 256]);
        ld_lds16(src + 1024, &tb->feat[(2 * w + 1) * 256]);
        if (w == 0) {
            const float* xs = px + (size_t)b * NN + n0;
            ld_lds4(xs + l,      &tb->x[0]);
            ld_lds4(xs + 64 + l, &tb->x[64]);
        } else if (w == 1) {
            ld_lds4(maskw + (((size_t)b * NN + n0) >> 1) + l, &tb->mask[0]);
        }
    };

    auto compute = [&](int bufi) {
        TileBuf* tb = &tiles[bufi];
#pragma unroll
        for (int ks = 0; ks < KS_PER_TILE; ++ks) {
            // packed-f32 weight chain: 4 element-pairs per K-step
            const f32x2* xp = (const f32x2*)&tb->x[ks * 32 + q * 8];
            frag_u a0, a1, a2, a3;
#pragma unroll
            for (int jp = 0; jp < 4; ++jp) {
                const f32x2 xv = xp[jp];
                const f32x2 dd = xv - gx2;
                const f32x2 tt = dd * dd;
                const f32x2 e3 = tt * c3v;
                const f32x2 e0 = tt * c0v;
                f32x2 w3, w0;
                w3[0] = __builtin_amdgcn_exp2f(e3[0]);
                w3[1] = __builtin_amdgcn_exp2f(e3[1]);
                w0[0] = __builtin_amdgcn_exp2f(e0[0]);
                w0[1] = __builtin_amdgcn_exp2f(e0[1]);
                f32x2 s2 = w3 * w3;
                const f32x2 w2 = s2 * s2;    // ^4 -> sigma 0.1
                f32x2 s1 = w2 * w2;
                const f32x2 w1 = s1 * s1;    // ^4 -> sigma 0.05
                a3.u[jp] = pack_bf16_trunc(w3[0], w3[1]);
                a2.u[jp] = pack_bf16_trunc(w2[0], w2[1]);
                a1.u[jp] = pack_bf16_trunc(w1[0], w1[1]);
                a0.u[jp] = pack_bf16_trunc(w0[0], w0[1]);
            }

            const bf16x8 amv = *(const bf16x8*)((const char*)tb->mask + ks * 64 + q * 16);
            const bf16x8 bf0 = *(const bf16x8*)&tb->feat[(ks * 2 + 0) * 256 + l * 4];
            const bf16x8 bf1 = *(const bf16x8*)&tb->feat[(ks * 2 + 1) * 256 + l * 4];

            acc[0][0] = __builtin_amdgcn_mfma_f32_16x16x32_bf16(a0.v, bf0, acc[0][0], 0, 0, 0);
            acc[0][1] = __builtin_amdgcn_mfma_f32_16x16x32_bf16(a0.v, bf1, acc[0][1], 0, 0, 0);
            dacc[0]   = __builtin_amdgcn_mfma_f32_16x16x32_bf16(a0.v, amv, dacc[0], 0, 0, 0);
            acc[1][0] = __builtin_amdgcn_mfma_f32_16x16x32_bf16(a1.v, bf0, acc[1][0], 0, 0, 0);
            acc[1][1] = __builtin_amdgcn_mfma_f32_16x16x32_bf16(a1.v, bf1, acc[1][1], 0, 0, 0);
            dacc[1]   = __builtin_amdgcn_mfma_f32_16x16x32_bf16(a1.v, amv, dacc[1], 0, 0, 0);
            acc[2][0] = __builtin_amdgcn_mfma_f32_16x16x32_bf16(a2.v, bf0, acc[2][0], 0, 0, 0);
            acc[2][1] = __builtin_amdgcn_mfma_f32_16x16x32_bf16(a2.v, bf1, acc[2][1], 0, 0, 0);
            dacc[2]   = __builtin_amdgcn_mfma_f32_16x16x32_bf16(a2.v, amv, dacc[2], 0, 0, 0);
            acc[3][0] = __builtin_amdgcn_mfma_f32_16x16x32_bf16(a3.v, bf0, acc[3][0], 0, 0, 0);
            acc[3][1] = __builtin_amdgcn_mfma_f32_16x16x32_bf16(a3.v, bf1, acc[3][1], 0, 0, 0);
            dacc[3]   = __builtin_amdgcn_mfma_f32_16x16x32_bf16(a3.v, amv, dacc[3], 0, 0, 0);
        }
    };

    stage(0, 0);
#pragma unroll 1
    for (int t = 0; t < T; ++t) {
        __syncthreads();                       // drains tile t's loads
        if (t + 1 < T) stage(t + 1, (t + 1) & 1);  // fly during compute(t)
        compute(t & 1);
    }

    // ---- epilogue. C/D layout: col(c) = lane&15 (+16h), row(g) = quad*4+reg
    if (!direct) {
        // partial layout per (b,g): words[0..63] = pack(acc[s][h=0], acc[s][h=1])
        // at index s*16+cl; floats[64..67] = dens[s].
        float* p = partial + ((size_t)nc * BB * GG + (size_t)b * GG + gbase) * PVALS;
        unsigned* pu = (unsigned*)p;
#pragma unroll
        for (int s = 0; s < NSIG; ++s)
#pragma unroll
            for (int r = 0; r < 4; ++r)
                pu[(q * 4 + r) * PVALS + s * 16 + cl] =
                    pack_bf16(acc[s][0][r], acc[s][1][r]);
        if (cl == 0) {
#pragma unroll
            for (int s = 0; s < NSIG; ++s)
#pragma unroll
                for (int r = 0; r < 4; ++r)
                    p[(q * 4 + r) * PVALS + 64 + s] = dacc[s][r];
        }
    } else {
        float* o0 = out0 + ((size_t)b * GG + gbase) * (NSIG * CC);
        float* o1 = out1 + ((size_t)b * GG + gbase) * NSIG;
#pragma unroll
        for (int s = 0; s < NSIG; ++s)
#pragma unroll
            for (int r = 0; r < 4; ++r) {
                const float dd = dacc[s][r];
                const float inv = 1.0f / fmaxf(dd, 1e-6f);
#pragma unroll
                for (int h = 0; h < 2; ++h)
                    o0[(q * 4 + r) * (NSIG * CC) + s * CC + h * 16 + cl] = acc[s][h][r] * inv;
                if (cl == 0) o1[(q * 4 + r) * NSIG + s] = dd;
            }
    }
}

// ---- reduce: sum packed partials over n-chunks, divide, write outputs ----
// nchunk==8 path fully unrolled so all loads are in flight.
__global__ __launch_bounds__(128) void gsc_reduce_kernel(
    const float* __restrict__ partial, float* __restrict__ out0,
    float* __restrict__ out1, int nchunk)
{
    const size_t bg = blockIdx.x;
    const int v  = threadIdx.x;  // 0..127 -> (s = v>>5, c = v&31)
    const int s  = v >> 5;
    const int c  = v & 31;
    const int cl = c & 15;
    const int h  = c >> 4;
    const float* p0 = partial + bg * PVALS;
    const size_t cstride = (size_t)BB * GG * PVALS;
    const int wi = s * 16 + cl;
    float num = 0.0f, dn = 0.0f;
    if (nchunk == 8) {
#pragma unroll
        for (int nc = 0; nc < 8; ++nc) {
            const float* p = p0 + nc * cstride;
            const unsigned word = __float_as_uint(p[wi]);
            num += __uint_as_float(h ? (word & 0xffff0000u) : (word << 16));
            dn  += p[64 + s];
        }
    } else {
        for (int nc = 0; nc < nchunk; ++nc) {
            const float* p = p0 + nc * cstride;
            const unsigned word = __float_as_uint(p[wi]);
            num += __uint_as_float(h ? (word & 0xffff0000u) : (word << 16));
            dn  += p[64 + s];
        }
    }
    out0[bg * 128 + v] = num / fmaxf(dn, 1e-6f);
    if (v < NSIG) {
        float d = 0.0f;
        if (nchunk == 8) {
#pragma unroll
            for (int nc = 0; nc < 8; ++nc)
                d += p0[nc * cstride + 64 + v];
        } else {
            for (int nc = 0; nc < nchunk; ++nc)
                d += p0[nc * cstride + 64 + v];
        }
        out1[bg * NSIG + v] = d;
    }
}

extern "C" void kernel_launch(void* const* d_in, const int* in_sizes, int n_in,
                              void* d_out, int out_size, void* d_ws, size_t ws_size,
                              hipStream_t stream) {
    const float* px = (const float*)d_in[0];  // [B,N]
    const float* pf = (const float*)d_in[1];  // [B,N,C]
    const float* pm = (const float*)d_in[2];  // [B,N]
    const float* gx = (const float*)d_in[3];  // [G]
    float* out0 = (float*)d_out;                          // [B,G,4*C]
    float* out1 = out0 + (size_t)BB * GG * NSIG * CC;     // [B,G,4]

    const size_t fragWords = (size_t)BB * 256 * 256;   // 1 MB
    const size_t maskWords = (size_t)BB * NN / 2;      // 32 KB
    unsigned* fragw = (unsigned*)d_ws;
    unsigned* maskw = fragw + fragWords;
    float* partial  = (float*)(maskw + maskWords);
    const size_t used  = (fragWords + maskWords) * 4;
    const size_t avail = ws_size > used ? ws_size - used : 0;
    const size_t per   = (size_t)BB * GG * PVALS * sizeof(float);

    int nchunk = 1, direct = 1;
    if (8 * per <= avail)      { nchunk = 8; direct = 0; }
    else if (4 * per <= avail) { nchunk = 4; direct = 0; }
    else if (2 * per <= avail) { nchunk = 2; direct = 0; }
    else if (per <= avail)     { nchunk = 1; direct = 0; }

    gsc_prep_kernel<<<dim3(BB * (NN / 2) * CC / 256), dim3(256), 0, stream>>>(
        pf, pm, fragw, maskw);
    gsc_mfma_kernel<<<dim3(BB * (GG / 64) * nchunk), dim3(256), 0, stream>>>(
        px, fragw, maskw, gx, partial, out0, out1, nchunk, direct);
    if (!direct)
        gsc_reduce_kernel<<<dim3(BB * GG), dim3(128), 0, stream>>>(
            partial, out0, out1, nchunk);
}